// Round 20
// baseline (156.139 us; speedup 1.0000x reference)
//
#include <hip/hip_runtime.h>
#include <hip/hip_bf16.h>
#include <hip/hip_fp8.h>

// AttnBlock: B=8, C=512, N=2048, G=32.
// R20 = R19 (154us) + VALU strength-reduction in both GEMM cores:
//   - staging src pointers precomputed per thread, advanced += BK per K-tile
//     (kills the per-tile v_lshl_add_u64 address recompute the m97 asm showed);
//   - LDS fragment-read offsets hoisted out of the K-loop (loop-invariant);
//   - cvt_w vectorized f32x4.
// Counters said VALUBusy ~50% >> MfmaUtil 27% on the 256-thread GEMMs -> VALU is
// the busiest pipe; address recompute is the bulk of it.
// Everything else identical to R19 (fp8 attention core, fused softmax, gn_reg,
// T2 swizzle, batch->XCD pinning).

typedef __attribute__((ext_vector_type(8))) short short8;
typedef __attribute__((ext_vector_type(4))) float f32x4;
typedef unsigned short u16;
typedef unsigned char u8;
typedef unsigned int u32;

#define BK 64

__device__ __forceinline__ u16 f2bf(float f) {
  __hip_bfloat16 h = __float2bfloat16(f);
  return __builtin_bit_cast(u16, h);
}
__device__ __forceinline__ float bf2f(u16 u) {
  return __uint_as_float(((u32)u) << 16);
}
__device__ __forceinline__ u8 f2fp8(float f) {
  __hip_fp8_e4m3 h(f);
  return __builtin_bit_cast(u8, h);
}
__device__ __forceinline__ float fp82f(u8 u) {
  __hip_fp8_e4m3 h = __builtin_bit_cast(__hip_fp8_e4m3, u);
  return (float)h;
}

__device__ __forceinline__ void gload_lds16(const void* g, void* l) {
  __builtin_amdgcn_global_load_lds((const __attribute__((address_space(1))) void*)g,
                                   (__attribute__((address_space(3))) void*)l, 16, 0, 0);
}

// bf16 GEMM (qk / v / proj).
// MODE 0: fp8 out = acc + bias[col]   MODE 1: fp8 out = acc + bias[row]
// MODE 4: f32 out = acc + bias[row] + aux[...] (residual)
template <int MODE>
__global__ __launch_bounds__(256) void gemm13(
    const u16* __restrict__ A, const u16* __restrict__ Bt, void* __restrict__ OutV,
    const float* __restrict__ bias, float* __restrict__ aux,
    int K, int lda, int ldb, int ldo, int GX, int mOffB,
    long sA, long sBt, long sOut, long sRes, float scale) {
  __shared__ __align__(16) u16 lds_all[2 * 128 * BK];  // 32 KB: As | Bs
  u16* As = lds_all;
  u16* Bs = lds_all + 128 * BK;

  const int gid = blockIdx.x;
  const int b = gid & 7;  // batch == XCD
  const int t0 = gid >> 3;
  const int bx = t0 % GX;
  const int by = t0 / GX;
  const int tid = threadIdx.x;
  const int lane = tid & 63;
  const int wid = tid >> 6;
  const int wm = (wid >> 1) * 64;
  const int wn = (wid & 1) * 64;
  const int m0 = by * 128 + b * mOffB;
  const int n0 = bx * 128;
  const int l15 = lane & 15;
  const int lhi = lane >> 4;
  const int sw = l15 & 7;

  // strength-reduced staging: src pointers advance by BK per tile; dst fixed
  const u16* aSrc[4];
  const u16* bSrc[4];
  u16* aDst[4];
  u16* bDst[4];
#pragma unroll
  for (int i = 0; i < 4; ++i) {
    const int c = tid + i * 256;
    const int row = c >> 3;
    const int gslot = (c & 7) ^ (row & 7);
    aSrc[i] = A + (long)b * sA + (long)(m0 + row) * lda + gslot * 8;
    bSrc[i] = Bt + (long)b * sBt + (long)(n0 + row) * ldb + gslot * 8;
    aDst[i] = As + c * 8;
    bDst[i] = Bs + c * 8;
  }
  // hoisted LDS fragment-read offsets (u16 elements), invariant across K
  int aOff[4][2], bOff[4][2];
#pragma unroll
  for (int mf = 0; mf < 4; ++mf)
#pragma unroll
    for (int kh = 0; kh < 2; ++kh) {
      aOff[mf][kh] = (wm + mf * 16 + l15) * BK + (((kh * 4 + lhi) ^ sw) * 8);
      bOff[mf][kh] = (wn + mf * 16 + l15) * BK + (((kh * 4 + lhi) ^ sw) * 8);
    }

  f32x4 acc[4][4];
#pragma unroll
  for (int i = 0; i < 4; ++i)
#pragma unroll
    for (int j = 0; j < 4; ++j) acc[i][j] = (f32x4){0.f, 0.f, 0.f, 0.f};

  const int T = K / BK;
  for (int t = 0; t < T; ++t) {
#pragma unroll
    for (int i = 0; i < 4; ++i) {
      gload_lds16(aSrc[i], aDst[i]);
      aSrc[i] += BK;
    }
#pragma unroll
    for (int i = 0; i < 4; ++i) {
      gload_lds16(bSrc[i], bDst[i]);
      bSrc[i] += BK;
    }
    __syncthreads();

#pragma unroll
    for (int kh = 0; kh < 2; ++kh) {
      short8 af[4], bf[4];
#pragma unroll
      for (int mf = 0; mf < 4; ++mf) af[mf] = *(const short8*)(As + aOff[mf][kh]);
#pragma unroll
      for (int nf = 0; nf < 4; ++nf) bf[nf] = *(const short8*)(Bs + bOff[nf][kh]);
#pragma unroll
      for (int mf = 0; mf < 4; ++mf)
#pragma unroll
        for (int nf = 0; nf < 4; ++nf)
          acc[mf][nf] = __builtin_amdgcn_mfma_f32_16x16x32_bf16(af[mf], bf[nf],
                                                                acc[mf][nf], 0, 0, 0);
    }
    __syncthreads();
  }

  const int rbase = m0 + wm + (lane >> 4) * 4;
  const int cbase = n0 + wn + l15;
#pragma unroll
  for (int mf = 0; mf < 4; ++mf) {
#pragma unroll
    for (int nf = 0; nf < 4; ++nf) {
#pragma unroll
      for (int i = 0; i < 4; ++i) {
        const int row = rbase + mf * 16 + i;
        const int col = cbase + nf * 16;
        const long oidx = (long)b * sOut + (long)row * ldo + col;
        const float v = acc[mf][nf][i];
        if (MODE == 0) {
          ((u8*)OutV)[oidx] = f2fp8(v + bias[col]);
        } else if (MODE == 1) {
          ((u8*)OutV)[oidx] = f2fp8(v + bias[row]);
        } else {
          const float r = aux[(long)b * sRes + (long)row * ldo + col];
          ((float*)OutV)[oidx] = v + bias[row] + r;
        }
      }
    }
  }
}

// fp8 GEMM (S / PV). BK=128 fp8 elements = 128B rows.
// MODE 2: fp8 out = exp(acc*scale); LDS rowsum reduce -> 1 atomicAdd/row
// MODE 5: bf16 out = acc / aux[b*sRes + row]
template <int MODE>
__global__ __launch_bounds__(256) void gemm_f8(
    const u8* __restrict__ A, const u8* __restrict__ Bt, void* __restrict__ OutV,
    float* __restrict__ aux,
    int K, int lda, int ldb, int ldo, int GX, int mOffB,
    long sA, long sBt, long sOut, long sRes, float scale) {
  __shared__ __align__(16) u8 lds_all[2 * 128 * 128];  // 32 KB
  u8* As = lds_all;
  u8* Bs = lds_all + 128 * 128;

  const int gid = blockIdx.x;
  const int b = gid & 7;
  const int t0 = gid >> 3;
  const int bx = t0 % GX;
  const int by = t0 / GX;
  const int tid = threadIdx.x;
  const int lane = tid & 63;
  const int wid = tid >> 6;
  const int wm = (wid >> 1) * 64;
  const int wn = (wid & 1) * 64;
  const int m0 = by * 128 + b * mOffB;
  const int n0 = bx * 128;
  const int l15 = lane & 15;
  const int lhi = lane >> 4;
  const int sw = l15 & 7;

  const u8* aSrc[4];
  const u8* bSrc[4];
  u8* aDst[4];
  u8* bDst[4];
#pragma unroll
  for (int i = 0; i < 4; ++i) {
    const int c = tid + i * 256;
    const int row = c >> 3;
    const int gslot = (c & 7) ^ (row & 7);
    aSrc[i] = A + (long)b * sA + (long)(m0 + row) * lda + gslot * 16;
    bSrc[i] = Bt + (long)b * sBt + (long)(n0 + row) * ldb + gslot * 16;
    aDst[i] = As + c * 16;
    bDst[i] = Bs + c * 16;
  }
  int aOff[4][4], bOff[4][4];  // [frag][kk] byte offsets
#pragma unroll
  for (int mf = 0; mf < 4; ++mf)
#pragma unroll
    for (int kk = 0; kk < 4; ++kk) {
      const int so = ((((kk << 1) + (lhi >> 1)) ^ sw) << 4) + (lhi & 1) * 8;
      aOff[mf][kk] = (wm + mf * 16 + l15) * 128 + so;
      bOff[mf][kk] = (wn + mf * 16 + l15) * 128 + so;
    }

  f32x4 acc[4][4];
#pragma unroll
  for (int i = 0; i < 4; ++i)
#pragma unroll
    for (int j = 0; j < 4; ++j) acc[i][j] = (f32x4){0.f, 0.f, 0.f, 0.f};

  const int T = K / 128;
  for (int t = 0; t < T; ++t) {
#pragma unroll
    for (int i = 0; i < 4; ++i) {
      gload_lds16(aSrc[i], aDst[i]);
      aSrc[i] += 128;
    }
#pragma unroll
    for (int i = 0; i < 4; ++i) {
      gload_lds16(bSrc[i], bDst[i]);
      bSrc[i] += 128;
    }
    __syncthreads();

#pragma unroll
    for (int kk = 0; kk < 4; ++kk) {
      long af[4], bf[4];
#pragma unroll
      for (int mf = 0; mf < 4; ++mf) af[mf] = *(const long*)(As + aOff[mf][kk]);
#pragma unroll
      for (int nf = 0; nf < 4; ++nf) bf[nf] = *(const long*)(Bs + bOff[nf][kk]);
#pragma unroll
      for (int mf = 0; mf < 4; ++mf)
#pragma unroll
        for (int nf = 0; nf < 4; ++nf)
          acc[mf][nf] = __builtin_amdgcn_mfma_f32_16x16x32_fp8_fp8(af[mf], bf[nf],
                                                                   acc[mf][nf], 0, 0, 0);
    }
    __syncthreads();
  }

  const int cbase = n0 + wn + l15;
  if constexpr (MODE == 2) {
    float* rs = (float*)lds_all;  // [128][33] floats (dead GEMM LDS)
#pragma unroll
    for (int mf = 0; mf < 4; ++mf) {
#pragma unroll
      for (int i = 0; i < 4; ++i) {
        const int rl = wm + mf * 16 + lhi * 4 + i;
        const int row = m0 + rl;
        float rsum = 0.f;
#pragma unroll
        for (int nf = 0; nf < 4; ++nf) {
          const int col = cbase + nf * 16;
          const long oidx = (long)b * sOut + (long)row * ldo + col;
          const u8 pe = f2fp8(__expf(acc[mf][nf][i] * scale));
          ((u8*)OutV)[oidx] = pe;
          rsum += fp82f(pe);
        }
        rs[rl * 33 + (wn >> 2) + l15] = rsum;
      }
    }
    __syncthreads();
    if (tid < 128) {
      float s = 0.f;
#pragma unroll
      for (int j = 0; j < 32; ++j) s += rs[tid * 33 + j];
      atomicAdd(&aux[(long)b * sRes + m0 + tid], s);
    }
  } else {
    const int rbase = m0 + wm + lhi * 4;
#pragma unroll
    for (int mf = 0; mf < 4; ++mf) {
#pragma unroll
      for (int nf = 0; nf < 4; ++nf) {
#pragma unroll
        for (int i = 0; i < 4; ++i) {
          const int row = rbase + mf * 16 + i;
          const int col = cbase + nf * 16;
          const long oidx = (long)b * sOut + (long)row * ldo + col;
          ((u16*)OutV)[oidx] = f2bf(acc[mf][nf][i] / aux[(long)b * sRes + row]);
        }
      }
    }
  }
}

// Single-pass register-resident GroupNorm + transpose (R18-proven).
__global__ __launch_bounds__(256) void gn_reg(
    const float* __restrict__ x, const float* __restrict__ gamma,
    const float* __restrict__ beta, u16* __restrict__ hT) {
  const int gid = blockIdx.x;
  const int b = gid & 7;
  const int g = gid >> 3;
  const float* px = x + ((long)b * 512 + g * 16) * 2048;
  const int tid = threadIdx.x;
  const int lane = tid & 63, wid = tid >> 6;

  u32 pk[64];
  float s = 0.f, ss = 0.f;
#pragma unroll
  for (int j = 0; j < 32; ++j) {
    const float4 u = ((const float4*)px)[tid + 256 * j];
    s += (u.x + u.y) + (u.z + u.w);
    ss += (u.x * u.x + u.y * u.y) + (u.z * u.z + u.w * u.w);
    pk[2 * j] = (u32)f2bf(u.x) | ((u32)f2bf(u.y) << 16);
    pk[2 * j + 1] = (u32)f2bf(u.z) | ((u32)f2bf(u.w) << 16);
  }
#pragma unroll
  for (int off = 32; off > 0; off >>= 1) {
    s += __shfl_xor(s, off, 64);
    ss += __shfl_xor(ss, off, 64);
  }
  __shared__ float rs4[4], rss4[4], ga[16], be[16];
  if (lane == 0) { rs4[wid] = s; rss4[wid] = ss; }
  __syncthreads();
  if (tid == 0) {
    s = rs4[0] + rs4[1] + rs4[2] + rs4[3];
    ss = rss4[0] + rss4[1] + rss4[2] + rss4[3];
    const float mean = s * (1.f / 32768.f);
    const float var = ss * (1.f / 32768.f) - mean * mean;
    rs4[0] = mean;
    rss4[0] = rsqrtf(var + 1e-6f);
  }
  __syncthreads();
  if (tid < 16) {
    const float gaa = gamma[g * 16 + tid] * rss4[0];
    ga[tid] = gaa;
    be[tid] = beta[g * 16 + tid] - rs4[0] * gaa;
  }
  __syncthreads();

  float gar[16], ber[16];
#pragma unroll
  for (int c = 0; c < 16; ++c) { gar[c] = ga[c]; ber[c] = be[c]; }

#pragma unroll
  for (int p = 0; p < 2; ++p) {
#pragma unroll
    for (int r = 0; r < 4; ++r) {
      const int n = 4 * tid + r + 1024 * p;
      u16 w[16];
#pragma unroll
      for (int c = 0; c < 16; ++c) {
        const u32 word = pk[2 * (2 * c + p) + (r >> 1)];
        const float xv = bf2f((u16)(word >> (16 * (r & 1))));
        w[c] = f2bf(xv * gar[c] + ber[c]);
      }
      u16* dst = hT + ((long)b * 2048 + n) * 512 + g * 16;
      *(short8*)dst = *(short8*)&w[0];
      *(short8*)(dst + 8) = *(short8*)&w[8];
    }
  }
}

// weights fp32->bf16 (wq|wk|wv|wp), f32x4 vectorized; z==0: bqk concat + rowsum zero
__global__ __launch_bounds__(256) void cvt_w(const float* __restrict__ w0,
                                             const float* __restrict__ w1,
                                             const float* __restrict__ w2,
                                             const float* __restrict__ w3,
                                             const float* __restrict__ bq,
                                             const float* __restrict__ bk,
                                             float* __restrict__ bqk,
                                             float* __restrict__ rowsum,
                                             u16* __restrict__ out) {
  const int z = blockIdx.y;
  const float* src = (z == 0) ? w0 : (z == 1) ? w1 : (z == 2) ? w2 : w3;
  const int i = blockIdx.x * 256 + threadIdx.x;  // f32x4 index, 65536 per matrix
  const float4 u = ((const float4*)src)[i];
  ushort4 o;
  o.x = f2bf(u.x); o.y = f2bf(u.y); o.z = f2bf(u.z); o.w = f2bf(u.w);
  *(ushort4*)(out + (long)z * 262144 + i * 4) = o;
  if (z == 0) {
    if (i < 1024) bqk[i] = (i < 512) ? bq[i] : bk[i - 512];
    if (i < 16384) rowsum[i] = 0.f;
  }
}

extern "C" void kernel_launch(void* const* d_in, const int* in_sizes, int n_in,
                              void* d_out, int out_size, void* d_ws, size_t ws_size,
                              hipStream_t stream) {
  const float* x = (const float*)d_in[0];
  const float* gs = (const float*)d_in[1];
  const float* gb = (const float*)d_in[2];
  const float* wq = (const float*)d_in[3];
  const float* bq = (const float*)d_in[4];
  const float* wk = (const float*)d_in[5];
  const float* bk = (const float*)d_in[6];
  const float* wv = (const float*)d_in[7];
  const float* bv = (const float*)d_in[8];
  const float* wp = (const float*)d_in[9];
  const float* bp = (const float*)d_in[10];

  char* ws = (char*)d_ws;
  float* bqk = (float*)(ws + 4096);        // 4 KB
  float* rowsum = (float*)(ws + 12288);    // 64 KB [B*2048]
  u16* hT = (u16*)(ws + 131072);           // [16384, 512] bf16, 16 MB
  u8* qkT8 = (u8*)(hT + 8388608);          // [16384, 1024] fp8, 16 MB (q|k)
  u8* vv8 = qkT8 + 16777216;               // [B, 512, 2048] fp8, 8 MB
  u8* S8 = vv8 + 8388608;                  // [B, 2048, 2048] fp8, 32 MB (holds P)
  u16* wb = (u16*)(S8 + 33554432);         // wq|wk|wv|wp bf16, 2 MB
  u16* attnT = hT;                         // alias: hT dead after qk + v GEMMs
  float* out = (float*)d_out;

  cvt_w<<<dim3(256, 4, 1), 256, 0, stream>>>(wq, wk, wv, wp, bq, bk, bqk, rowsum, wb);
  gn_reg<<<dim3(256), 256, 0, stream>>>(x, gs, gb, hT);

  // qk: M=16384 (m0=by*128+b*2048), N=1024, K=512 -> fp8 out; 1024 blocks
  gemm13<0><<<dim3(1024), 256, 0, stream>>>(
      hT, wb, qkT8, bqk, nullptr, 512, 512, 512, 1024, 8, 2048, 0, 0, 0, 0, 0.f);
  // v: M=512, N=2048, K=512 -> fp8 out; per-b 4m x 16n -> 512 blocks
  gemm13<1><<<dim3(512), 256, 0, stream>>>(
      wb + 524288, hT, vv8, bv, nullptr, 512, 512, 512, 2048, 16, 0, 0, 1048576,
      1048576, 0, 0.f);
  // S: fp8 GEMM, M=N=2048, K=512; per-b 16m x 16n -> 2048 blocks; exp + rowsum
  gemm_f8<2><<<dim3(2048), 256, 0, stream>>>(
      qkT8, qkT8 + 512, S8, rowsum, 512, 1024, 1024, 2048, 16, 0, 2097152, 2097152,
      4194304, 2048, 0.04419417382415922f);
  // PV: fp8 GEMM, M=2048, N=512, K=2048; per-b 16m x 4n -> 512 blocks; / rowsum
  gemm_f8<5><<<dim3(512), 256, 0, stream>>>(
      S8, vv8, attnT, rowsum, 2048, 2048, 2048, 512, 4, 0, 4194304, 1048576,
      1048576, 2048, 0.f);
  // proj+residual: M=512, N=2048, K=512; per-b 4m x 16n -> 512 blocks
  gemm13<4><<<dim3(512), 256, 0, stream>>>(
      wb + 786432, attnT, out, bp, (float*)x, 512, 512, 512, 2048, 16, 0, 0, 1048576,
      1048576, 1048576, 0.f);
}

// Round 21
// 136.089 us; speedup vs baseline: 1.1473x; 1.1473x over previous
//
#include <hip/hip_runtime.h>
#include <hip/hip_bf16.h>
#include <hip/hip_fp8.h>

// AttnBlock: B=8, C=512, N=2048, G=32.
// R21 = R19 (154us, best) with the fp8 attention GEMMs (S, PV) moved to the
// MX-scaled MFMA:  __builtin_amdgcn_mfma_scale_f32_16x16x128_f8f6f4
//   - K=128 per instruction -> 4x fewer MFMA issues, ~2x matrix rate
//     (guide m148: 995 -> 1628 TF on this exact m97 structure).
//   - scales = 1.0 (E8M0 byte 127 -> 0x7F7F7F7F, opsel 0): bit-identical math
//     to the non-scaled fp8 path. cbsz=0/blgp=0 = e4m3 A/B.
//   - fragment = two adjacent swizzled 16B slots per lane (k = 32*lhi + 0..31);
//     C/D layout shape-determined -> epilogues unchanged.
// Everything else identical to R19 (bf16 qk/v/proj GEMMs with fp8 outputs,
// fused exp+rowsum softmax, gn_reg, T2 swizzle, batch->XCD pinning).

typedef __attribute__((ext_vector_type(8))) short short8;
typedef __attribute__((ext_vector_type(4))) float f32x4;
typedef __attribute__((ext_vector_type(8))) int i32x8;
typedef __attribute__((ext_vector_type(4))) int i32x4;
typedef unsigned short u16;
typedef unsigned char u8;
typedef unsigned int u32;

#define BK 64

__device__ __forceinline__ u16 f2bf(float f) {
  __hip_bfloat16 h = __float2bfloat16(f);
  return __builtin_bit_cast(u16, h);
}
__device__ __forceinline__ float bf2f(u16 u) {
  return __uint_as_float(((u32)u) << 16);
}
__device__ __forceinline__ u8 f2fp8(float f) {
  __hip_fp8_e4m3 h(f);
  return __builtin_bit_cast(u8, h);
}
__device__ __forceinline__ float fp82f(u8 u) {
  __hip_fp8_e4m3 h = __builtin_bit_cast(__hip_fp8_e4m3, u);
  return (float)h;
}

__device__ __forceinline__ void gload_lds16(const void* g, void* l) {
  __builtin_amdgcn_global_load_lds((const __attribute__((address_space(1))) void*)g,
                                   (__attribute__((address_space(3))) void*)l, 16, 0, 0);
}

// bf16 GEMM (qk / v / proj) — R19-proven.
// MODE 0: fp8 out = acc + bias[col]   MODE 1: fp8 out = acc + bias[row]
// MODE 4: f32 out = acc + bias[row] + aux[...] (residual)
template <int MODE>
__global__ __launch_bounds__(256) void gemm13(
    const u16* __restrict__ A, const u16* __restrict__ Bt, void* __restrict__ OutV,
    const float* __restrict__ bias, float* __restrict__ aux,
    int K, int lda, int ldb, int ldo, int GX, int mOffB,
    long sA, long sBt, long sOut, long sRes, float scale) {
  __shared__ __align__(16) u16 lds_all[2 * 128 * BK];  // 32 KB: As | Bs
  u16* As = lds_all;
  u16* Bs = lds_all + 128 * BK;

  const int gid = blockIdx.x;
  const int b = gid & 7;  // batch == XCD
  const int t0 = gid >> 3;
  const int bx = t0 % GX;
  const int by = t0 / GX;
  const u16* Ab = A + (long)b * sA;
  const u16* Bb = Bt + (long)b * sBt;
  const int tid = threadIdx.x;
  const int lane = tid & 63;
  const int wid = tid >> 6;
  const int wm = (wid >> 1) * 64;
  const int wn = (wid & 1) * 64;
  const int m0 = by * 128 + b * mOffB;
  const int n0 = bx * 128;
  const int l15 = lane & 15;
  const int lhi = lane >> 4;
  const int sw = l15 & 7;

  f32x4 acc[4][4];
#pragma unroll
  for (int i = 0; i < 4; ++i)
#pragma unroll
    for (int j = 0; j < 4; ++j) acc[i][j] = (f32x4){0.f, 0.f, 0.f, 0.f};

  for (int ks = 0; ks < K; ks += BK) {
#pragma unroll
    for (int i = 0; i < 4; ++i) {
      const int c = tid + i * 256;
      const int row = c >> 3;
      const int gslot = (c & 7) ^ (row & 7);
      gload_lds16(Ab + (long)(m0 + row) * lda + ks + gslot * 8, (void*)(As + c * 8));
    }
#pragma unroll
    for (int i = 0; i < 4; ++i) {
      const int c = tid + i * 256;
      const int row = c >> 3;
      const int gslot = (c & 7) ^ (row & 7);
      gload_lds16(Bb + (long)(n0 + row) * ldb + ks + gslot * 8, (void*)(Bs + c * 8));
    }
    __syncthreads();

#pragma unroll
    for (int kh = 0; kh < 2; ++kh) {
      short8 af[4], bf[4];
#pragma unroll
      for (int mf = 0; mf < 4; ++mf)
        af[mf] = *(const short8*)(As + (wm + mf * 16 + l15) * BK +
                                  ((kh * 4 + lhi) ^ sw) * 8);
#pragma unroll
      for (int nf = 0; nf < 4; ++nf)
        bf[nf] = *(const short8*)(Bs + (wn + nf * 16 + l15) * BK +
                                  ((kh * 4 + lhi) ^ sw) * 8);
#pragma unroll
      for (int mf = 0; mf < 4; ++mf)
#pragma unroll
        for (int nf = 0; nf < 4; ++nf)
          acc[mf][nf] = __builtin_amdgcn_mfma_f32_16x16x32_bf16(af[mf], bf[nf],
                                                                acc[mf][nf], 0, 0, 0);
    }
    __syncthreads();
  }

  const int rbase = m0 + wm + lhi * 4;
  const int cbase = n0 + wn + l15;
#pragma unroll
  for (int mf = 0; mf < 4; ++mf) {
#pragma unroll
    for (int nf = 0; nf < 4; ++nf) {
#pragma unroll
      for (int i = 0; i < 4; ++i) {
        const int row = rbase + mf * 16 + i;
        const int col = cbase + nf * 16;
        const long oidx = (long)b * sOut + (long)row * ldo + col;
        const float v = acc[mf][nf][i];
        if (MODE == 0) {
          ((u8*)OutV)[oidx] = f2fp8(v + bias[col]);
        } else if (MODE == 1) {
          ((u8*)OutV)[oidx] = f2fp8(v + bias[row]);
        } else {
          const float r = aux[(long)b * sRes + (long)row * ldo + col];
          ((float*)OutV)[oidx] = v + bias[row] + r;
        }
      }
    }
  }
}

// MX-scaled fp8 GEMM (S / PV). K-tile = 128 fp8 elements = 128B rows (staging
// and swizzle byte-identical to R19's gemm_f8). One scaled MFMA consumes K=128.
// MODE 2: fp8 out = exp(acc*scale); LDS rowsum reduce -> 1 atomicAdd/row
// MODE 5: bf16 out = acc / aux[b*sRes + row]
template <int MODE>
__global__ __launch_bounds__(256) void gemm_mx(
    const u8* __restrict__ A, const u8* __restrict__ Bt, void* __restrict__ OutV,
    float* __restrict__ aux,
    int K, int lda, int ldb, int ldo, int GX, int mOffB,
    long sA, long sBt, long sOut, long sRes, float scale) {
  __shared__ __align__(16) u8 lds_all[2 * 128 * 128];  // 32 KB: As | Bs
  u8* As = lds_all;
  u8* Bs = lds_all + 128 * 128;

  const int gid = blockIdx.x;
  const int b = gid & 7;
  const int t0 = gid >> 3;
  const int bx = t0 % GX;
  const int by = t0 / GX;
  const u8* Ab = A + (long)b * sA;
  const u8* Bb = Bt + (long)b * sBt;
  const int tid = threadIdx.x;
  const int lane = tid & 63;
  const int wid = tid >> 6;
  const int wm = (wid >> 1) * 64;
  const int wn = (wid & 1) * 64;
  const int m0 = by * 128 + b * mOffB;
  const int n0 = bx * 128;
  const int l15 = lane & 15;
  const int lhi = lane >> 4;
  const int sw = l15 & 7;
  // per-fragment slot pair (k = 32*lhi .. 32*lhi+31), swizzled
  const int slo = ((2 * lhi) ^ sw) * 16;
  const int shi = ((2 * lhi + 1) ^ sw) * 16;

  f32x4 acc[4][4];
#pragma unroll
  for (int i = 0; i < 4; ++i)
#pragma unroll
    for (int j = 0; j < 4; ++j) acc[i][j] = (f32x4){0.f, 0.f, 0.f, 0.f};

  const int T = K / 128;
  for (int t = 0; t < T; ++t) {
    const int ks = t * 128;
#pragma unroll
    for (int i = 0; i < 4; ++i) {
      const int c = tid + i * 256;
      const int row = c >> 3;
      const int gslot = (c & 7) ^ (row & 7);
      gload_lds16(Ab + (long)(m0 + row) * lda + ks + gslot * 16, (void*)(As + c * 16));
    }
#pragma unroll
    for (int i = 0; i < 4; ++i) {
      const int c = tid + i * 256;
      const int row = c >> 3;
      const int gslot = (c & 7) ^ (row & 7);
      gload_lds16(Bb + (long)(n0 + row) * ldb + ks + gslot * 16, (void*)(Bs + c * 16));
    }
    __syncthreads();

    i32x8 af[4], bf[4];
#pragma unroll
    for (int mf = 0; mf < 4; ++mf) {
      const u8* base = As + (wm + mf * 16 + l15) * 128;
      const i32x4 lo = *(const i32x4*)(base + slo);
      const i32x4 hi = *(const i32x4*)(base + shi);
      af[mf][0] = lo[0]; af[mf][1] = lo[1]; af[mf][2] = lo[2]; af[mf][3] = lo[3];
      af[mf][4] = hi[0]; af[mf][5] = hi[1]; af[mf][6] = hi[2]; af[mf][7] = hi[3];
    }
#pragma unroll
    for (int nf = 0; nf < 4; ++nf) {
      const u8* base = Bs + (wn + nf * 16 + l15) * 128;
      const i32x4 lo = *(const i32x4*)(base + slo);
      const i32x4 hi = *(const i32x4*)(base + shi);
      bf[nf][0] = lo[0]; bf[nf][1] = lo[1]; bf[nf][2] = lo[2]; bf[nf][3] = lo[3];
      bf[nf][4] = hi[0]; bf[nf][5] = hi[1]; bf[nf][6] = hi[2]; bf[nf][7] = hi[3];
    }
#pragma unroll
    for (int mf = 0; mf < 4; ++mf)
#pragma unroll
      for (int nf = 0; nf < 4; ++nf)
        acc[mf][nf] = __builtin_amdgcn_mfma_scale_f32_16x16x128_f8f6f4(
            af[mf], bf[nf], acc[mf][nf], 0 /*cbsz: e4m3*/, 0 /*blgp: e4m3*/,
            0, 0x7F7F7F7F /*scaleA = 1.0*/, 0, 0x7F7F7F7F /*scaleB = 1.0*/);
    __syncthreads();
  }

  const int cbase = n0 + wn + l15;
  if constexpr (MODE == 2) {
    float* rs = (float*)lds_all;  // [128][33] floats (dead GEMM LDS)
#pragma unroll
    for (int mf = 0; mf < 4; ++mf) {
#pragma unroll
      for (int i = 0; i < 4; ++i) {
        const int rl = wm + mf * 16 + lhi * 4 + i;
        const int row = m0 + rl;
        float rsum = 0.f;
#pragma unroll
        for (int nf = 0; nf < 4; ++nf) {
          const int col = cbase + nf * 16;
          const long oidx = (long)b * sOut + (long)row * ldo + col;
          const u8 pe = f2fp8(__expf(acc[mf][nf][i] * scale));
          ((u8*)OutV)[oidx] = pe;
          rsum += fp82f(pe);  // sum what PV will actually read
        }
        rs[rl * 33 + (wn >> 2) + l15] = rsum;
      }
    }
    __syncthreads();
    if (tid < 128) {
      float s = 0.f;
#pragma unroll
      for (int j = 0; j < 32; ++j) s += rs[tid * 33 + j];
      atomicAdd(&aux[(long)b * sRes + m0 + tid], s);
    }
  } else {
    const int rbase = m0 + wm + lhi * 4;
#pragma unroll
    for (int mf = 0; mf < 4; ++mf) {
#pragma unroll
      for (int nf = 0; nf < 4; ++nf) {
#pragma unroll
        for (int i = 0; i < 4; ++i) {
          const int row = rbase + mf * 16 + i;
          const int col = cbase + nf * 16;
          const long oidx = (long)b * sOut + (long)row * ldo + col;
          ((u16*)OutV)[oidx] = f2bf(acc[mf][nf][i] / aux[(long)b * sRes + row]);
        }
      }
    }
  }
}

// Single-pass register-resident GroupNorm + transpose (R18-proven).
__global__ __launch_bounds__(256) void gn_reg(
    const float* __restrict__ x, const float* __restrict__ gamma,
    const float* __restrict__ beta, u16* __restrict__ hT) {
  const int gid = blockIdx.x;
  const int b = gid & 7;
  const int g = gid >> 3;
  const float* px = x + ((long)b * 512 + g * 16) * 2048;
  const int tid = threadIdx.x;
  const int lane = tid & 63, wid = tid >> 6;

  u32 pk[64];
  float s = 0.f, ss = 0.f;
#pragma unroll
  for (int j = 0; j < 32; ++j) {
    const float4 u = ((const float4*)px)[tid + 256 * j];
    s += (u.x + u.y) + (u.z + u.w);
    ss += (u.x * u.x + u.y * u.y) + (u.z * u.z + u.w * u.w);
    pk[2 * j] = (u32)f2bf(u.x) | ((u32)f2bf(u.y) << 16);
    pk[2 * j + 1] = (u32)f2bf(u.z) | ((u32)f2bf(u.w) << 16);
  }
#pragma unroll
  for (int off = 32; off > 0; off >>= 1) {
    s += __shfl_xor(s, off, 64);
    ss += __shfl_xor(ss, off, 64);
  }
  __shared__ float rs4[4], rss4[4], ga[16], be[16];
  if (lane == 0) { rs4[wid] = s; rss4[wid] = ss; }
  __syncthreads();
  if (tid == 0) {
    s = rs4[0] + rs4[1] + rs4[2] + rs4[3];
    ss = rss4[0] + rss4[1] + rss4[2] + rss4[3];
    const float mean = s * (1.f / 32768.f);
    const float var = ss * (1.f / 32768.f) - mean * mean;
    rs4[0] = mean;
    rss4[0] = rsqrtf(var + 1e-6f);
  }
  __syncthreads();
  if (tid < 16) {
    const float gaa = gamma[g * 16 + tid] * rss4[0];
    ga[tid] = gaa;
    be[tid] = beta[g * 16 + tid] - rs4[0] * gaa;
  }
  __syncthreads();

  float gar[16], ber[16];
#pragma unroll
  for (int c = 0; c < 16; ++c) { gar[c] = ga[c]; ber[c] = be[c]; }

#pragma unroll
  for (int p = 0; p < 2; ++p) {
#pragma unroll
    for (int r = 0; r < 4; ++r) {
      const int n = 4 * tid + r + 1024 * p;
      u16 w[16];
#pragma unroll
      for (int c = 0; c < 16; ++c) {
        const u32 word = pk[2 * (2 * c + p) + (r >> 1)];
        const float xv = bf2f((u16)(word >> (16 * (r & 1))));
        w[c] = f2bf(xv * gar[c] + ber[c]);
      }
      u16* dst = hT + ((long)b * 2048 + n) * 512 + g * 16;
      *(short8*)dst = *(short8*)&w[0];
      *(short8*)(dst + 8) = *(short8*)&w[8];
    }
  }
}

// weights fp32->bf16 (wq|wk|wv|wp); z==0 blocks also: bqk concat + rowsum zero
__global__ __launch_bounds__(256) void cvt_w(const float* __restrict__ w0,
                                             const float* __restrict__ w1,
                                             const float* __restrict__ w2,
                                             const float* __restrict__ w3,
                                             const float* __restrict__ bq,
                                             const float* __restrict__ bk,
                                             float* __restrict__ bqk,
                                             float* __restrict__ rowsum,
                                             u16* __restrict__ out) {
  const int z = blockIdx.y;
  const float* src = (z == 0) ? w0 : (z == 1) ? w1 : (z == 2) ? w2 : w3;
  const int i = blockIdx.x * 256 + threadIdx.x;
  out[(long)z * 262144 + i] = f2bf(src[i]);
  if (z == 0) {
    if (i < 1024) bqk[i] = (i < 512) ? bq[i] : bk[i - 512];
    if (i < 16384) rowsum[i] = 0.f;
  }
}

extern "C" void kernel_launch(void* const* d_in, const int* in_sizes, int n_in,
                              void* d_out, int out_size, void* d_ws, size_t ws_size,
                              hipStream_t stream) {
  const float* x = (const float*)d_in[0];
  const float* gs = (const float*)d_in[1];
  const float* gb = (const float*)d_in[2];
  const float* wq = (const float*)d_in[3];
  const float* bq = (const float*)d_in[4];
  const float* wk = (const float*)d_in[5];
  const float* bk = (const float*)d_in[6];
  const float* wv = (const float*)d_in[7];
  const float* bv = (const float*)d_in[8];
  const float* wp = (const float*)d_in[9];
  const float* bp = (const float*)d_in[10];

  char* ws = (char*)d_ws;
  float* bqk = (float*)(ws + 4096);        // 4 KB
  float* rowsum = (float*)(ws + 12288);    // 64 KB [B*2048]
  u16* hT = (u16*)(ws + 131072);           // [16384, 512] bf16, 16 MB
  u8* qkT8 = (u8*)(hT + 8388608);          // [16384, 1024] fp8, 16 MB (q|k)
  u8* vv8 = qkT8 + 16777216;               // [B, 512, 2048] fp8, 8 MB
  u8* S8 = vv8 + 8388608;                  // [B, 2048, 2048] fp8, 32 MB (holds P)
  u16* wb = (u16*)(S8 + 33554432);         // wq|wk|wv|wp bf16, 2 MB
  u16* attnT = hT;                         // alias: hT dead after qk + v GEMMs
  float* out = (float*)d_out;

  cvt_w<<<dim3(1024, 4, 1), 256, 0, stream>>>(wq, wk, wv, wp, bq, bk, bqk, rowsum, wb);
  gn_reg<<<dim3(256), 256, 0, stream>>>(x, gs, gb, hT);

  // qk: M=16384 (m0=by*128+b*2048), N=1024, K=512 -> fp8 out; 1024 blocks
  gemm13<0><<<dim3(1024), 256, 0, stream>>>(
      hT, wb, qkT8, bqk, nullptr, 512, 512, 512, 1024, 8, 2048, 0, 0, 0, 0, 0.f);
  // v: M=512, N=2048, K=512 -> fp8 out; per-b 4m x 16n -> 512 blocks
  gemm13<1><<<dim3(512), 256, 0, stream>>>(
      wb + 524288, hT, vv8, bv, nullptr, 512, 512, 512, 2048, 16, 0, 0, 1048576,
      1048576, 0, 0.f);
  // S: MX fp8 GEMM, M=N=2048, K=512; per-b 16m x 16n -> 2048 blocks; exp + rowsum
  gemm_mx<2><<<dim3(2048), 256, 0, stream>>>(
      qkT8, qkT8 + 512, S8, rowsum, 512, 1024, 1024, 2048, 16, 0, 2097152, 2097152,
      4194304, 2048, 0.04419417382415922f);
  // PV: MX fp8 GEMM, M=2048, N=512, K=2048; per-b 16m x 4n -> 512 blocks; / rowsum
  gemm_mx<5><<<dim3(512), 256, 0, stream>>>(
      S8, vv8, attnT, rowsum, 2048, 2048, 2048, 512, 4, 0, 4194304, 1048576,
      1048576, 2048, 0.f);
  // proj+residual: M=512, N=2048, K=512; per-b 4m x 16n -> 512 blocks
  gemm13<4><<<dim3(512), 256, 0, stream>>>(
      wb + 786432, attnT, out, bp, (float*)x, 512, 512, 512, 2048, 16, 0, 0, 1048576,
      1048576, 1048576, 0.f);
}

// Round 22
// 120.567 us; speedup vs baseline: 1.2950x; 1.1287x over previous
//
#include <hip/hip_runtime.h>
#include <hip/hip_bf16.h>
#include <hip/hip_fp8.h>

// AttnBlock: B=8, C=512, N=2048, G=32.
// R22 = R21 (136us) + MX-fp8 extended to qk and v GEMMs:
//   - gn_reg writes hT as fp8 (e4m3; |h| <= ~5, well in range);
//   - cvt_w writes wq|wk and wv as fp8, wp stays bf16 (accuracy margin);
//   - qk and v run gemm_mx (K=128/instr scaled MFMA) with new bias modes;
//   - proj stays bf16 (gemm13<4>); attnT gets its own buffer.
// S/PV MX path unchanged (R21-proven: scale=1.0 bit-identical, +18us win).
// Keeps: fused exp+rowsum softmax, T2 swizzle, batch->XCD pinning.

typedef __attribute__((ext_vector_type(8))) short short8;
typedef __attribute__((ext_vector_type(4))) float f32x4;
typedef __attribute__((ext_vector_type(8))) int i32x8;
typedef __attribute__((ext_vector_type(4))) int i32x4;
typedef unsigned short u16;
typedef unsigned char u8;
typedef unsigned int u32;

#define BK 64

__device__ __forceinline__ u16 f2bf(float f) {
  __hip_bfloat16 h = __float2bfloat16(f);
  return __builtin_bit_cast(u16, h);
}
__device__ __forceinline__ float bf2f(u16 u) {
  return __uint_as_float(((u32)u) << 16);
}
__device__ __forceinline__ u8 f2fp8(float f) {
  __hip_fp8_e4m3 h(f);
  return __builtin_bit_cast(u8, h);
}
__device__ __forceinline__ float fp82f(u8 u) {
  __hip_fp8_e4m3 h = __builtin_bit_cast(__hip_fp8_e4m3, u);
  return (float)h;
}

__device__ __forceinline__ void gload_lds16(const void* g, void* l) {
  __builtin_amdgcn_global_load_lds((const __attribute__((address_space(1))) void*)g,
                                   (__attribute__((address_space(3))) void*)l, 16, 0, 0);
}

// bf16 GEMM (proj only now).
// MODE 4: f32 out = acc + bias[row] + aux[...] (residual)
template <int MODE>
__global__ __launch_bounds__(256) void gemm13(
    const u16* __restrict__ A, const u16* __restrict__ Bt, void* __restrict__ OutV,
    const float* __restrict__ bias, float* __restrict__ aux,
    int K, int lda, int ldb, int ldo, int GX, int mOffB,
    long sA, long sBt, long sOut, long sRes, float scale) {
  __shared__ __align__(16) u16 lds_all[2 * 128 * BK];  // 32 KB: As | Bs
  u16* As = lds_all;
  u16* Bs = lds_all + 128 * BK;

  const int gid = blockIdx.x;
  const int b = gid & 7;  // batch == XCD
  const int t0 = gid >> 3;
  const int bx = t0 % GX;
  const int by = t0 / GX;
  const u16* Ab = A + (long)b * sA;
  const u16* Bb = Bt + (long)b * sBt;
  const int tid = threadIdx.x;
  const int lane = tid & 63;
  const int wid = tid >> 6;
  const int wm = (wid >> 1) * 64;
  const int wn = (wid & 1) * 64;
  const int m0 = by * 128 + b * mOffB;
  const int n0 = bx * 128;
  const int l15 = lane & 15;
  const int lhi = lane >> 4;
  const int sw = l15 & 7;

  f32x4 acc[4][4];
#pragma unroll
  for (int i = 0; i < 4; ++i)
#pragma unroll
    for (int j = 0; j < 4; ++j) acc[i][j] = (f32x4){0.f, 0.f, 0.f, 0.f};

  for (int ks = 0; ks < K; ks += BK) {
#pragma unroll
    for (int i = 0; i < 4; ++i) {
      const int c = tid + i * 256;
      const int row = c >> 3;
      const int gslot = (c & 7) ^ (row & 7);
      gload_lds16(Ab + (long)(m0 + row) * lda + ks + gslot * 8, (void*)(As + c * 8));
    }
#pragma unroll
    for (int i = 0; i < 4; ++i) {
      const int c = tid + i * 256;
      const int row = c >> 3;
      const int gslot = (c & 7) ^ (row & 7);
      gload_lds16(Bb + (long)(n0 + row) * ldb + ks + gslot * 8, (void*)(Bs + c * 8));
    }
    __syncthreads();

#pragma unroll
    for (int kh = 0; kh < 2; ++kh) {
      short8 af[4], bf[4];
#pragma unroll
      for (int mf = 0; mf < 4; ++mf)
        af[mf] = *(const short8*)(As + (wm + mf * 16 + l15) * BK +
                                  ((kh * 4 + lhi) ^ sw) * 8);
#pragma unroll
      for (int nf = 0; nf < 4; ++nf)
        bf[nf] = *(const short8*)(Bs + (wn + nf * 16 + l15) * BK +
                                  ((kh * 4 + lhi) ^ sw) * 8);
#pragma unroll
      for (int mf = 0; mf < 4; ++mf)
#pragma unroll
        for (int nf = 0; nf < 4; ++nf)
          acc[mf][nf] = __builtin_amdgcn_mfma_f32_16x16x32_bf16(af[mf], bf[nf],
                                                                acc[mf][nf], 0, 0, 0);
    }
    __syncthreads();
  }

  const int rbase = m0 + wm + lhi * 4;
  const int cbase = n0 + wn + l15;
#pragma unroll
  for (int mf = 0; mf < 4; ++mf) {
#pragma unroll
    for (int nf = 0; nf < 4; ++nf) {
#pragma unroll
      for (int i = 0; i < 4; ++i) {
        const int row = rbase + mf * 16 + i;
        const int col = cbase + nf * 16;
        const long oidx = (long)b * sOut + (long)row * ldo + col;
        const float v = acc[mf][nf][i];
        const float r = aux[(long)b * sRes + (long)row * ldo + col];
        ((float*)OutV)[oidx] = v + bias[row] + r;
      }
    }
  }
}

// MX-scaled fp8 GEMM. K-tile = 128 fp8 elements = 128B rows; scale=1.0 pinned.
// MODE 0: fp8 out = acc + bias[col]       MODE 1: fp8 out = acc + bias[row]
// MODE 2: fp8 out = exp(acc*scale); LDS rowsum reduce -> 1 atomicAdd/row
// MODE 5: bf16 out = acc / aux[b*sRes + row]
template <int MODE>
__global__ __launch_bounds__(256) void gemm_mx(
    const u8* __restrict__ A, const u8* __restrict__ Bt, void* __restrict__ OutV,
    const float* __restrict__ bias, float* __restrict__ aux,
    int K, int lda, int ldb, int ldo, int GX, int mOffB,
    long sA, long sBt, long sOut, long sRes, float scale) {
  __shared__ __align__(16) u8 lds_all[2 * 128 * 128];  // 32 KB: As | Bs
  u8* As = lds_all;
  u8* Bs = lds_all + 128 * 128;

  const int gid = blockIdx.x;
  const int b = gid & 7;
  const int t0 = gid >> 3;
  const int bx = t0 % GX;
  const int by = t0 / GX;
  const u8* Ab = A + (long)b * sA;
  const u8* Bb = Bt + (long)b * sBt;
  const int tid = threadIdx.x;
  const int lane = tid & 63;
  const int wid = tid >> 6;
  const int wm = (wid >> 1) * 64;
  const int wn = (wid & 1) * 64;
  const int m0 = by * 128 + b * mOffB;
  const int n0 = bx * 128;
  const int l15 = lane & 15;
  const int lhi = lane >> 4;
  const int sw = l15 & 7;
  const int slo = ((2 * lhi) ^ sw) * 16;
  const int shi = ((2 * lhi + 1) ^ sw) * 16;

  f32x4 acc[4][4];
#pragma unroll
  for (int i = 0; i < 4; ++i)
#pragma unroll
    for (int j = 0; j < 4; ++j) acc[i][j] = (f32x4){0.f, 0.f, 0.f, 0.f};

  const int T = K / 128;
  for (int t = 0; t < T; ++t) {
    const int ks = t * 128;
#pragma unroll
    for (int i = 0; i < 4; ++i) {
      const int c = tid + i * 256;
      const int row = c >> 3;
      const int gslot = (c & 7) ^ (row & 7);
      gload_lds16(Ab + (long)(m0 + row) * lda + ks + gslot * 16, (void*)(As + c * 16));
    }
#pragma unroll
    for (int i = 0; i < 4; ++i) {
      const int c = tid + i * 256;
      const int row = c >> 3;
      const int gslot = (c & 7) ^ (row & 7);
      gload_lds16(Bb + (long)(n0 + row) * ldb + ks + gslot * 16, (void*)(Bs + c * 16));
    }
    __syncthreads();

    i32x8 af[4], bf[4];
#pragma unroll
    for (int mf = 0; mf < 4; ++mf) {
      const u8* base = As + (wm + mf * 16 + l15) * 128;
      const i32x4 lo = *(const i32x4*)(base + slo);
      const i32x4 hi = *(const i32x4*)(base + shi);
      af[mf][0] = lo[0]; af[mf][1] = lo[1]; af[mf][2] = lo[2]; af[mf][3] = lo[3];
      af[mf][4] = hi[0]; af[mf][5] = hi[1]; af[mf][6] = hi[2]; af[mf][7] = hi[3];
    }
#pragma unroll
    for (int nf = 0; nf < 4; ++nf) {
      const u8* base = Bs + (wn + nf * 16 + l15) * 128;
      const i32x4 lo = *(const i32x4*)(base + slo);
      const i32x4 hi = *(const i32x4*)(base + shi);
      bf[nf][0] = lo[0]; bf[nf][1] = lo[1]; bf[nf][2] = lo[2]; bf[nf][3] = lo[3];
      bf[nf][4] = hi[0]; bf[nf][5] = hi[1]; bf[nf][6] = hi[2]; bf[nf][7] = hi[3];
    }
#pragma unroll
    for (int mf = 0; mf < 4; ++mf)
#pragma unroll
      for (int nf = 0; nf < 4; ++nf)
        acc[mf][nf] = __builtin_amdgcn_mfma_scale_f32_16x16x128_f8f6f4(
            af[mf], bf[nf], acc[mf][nf], 0, 0, 0, 0x7F7F7F7F, 0, 0x7F7F7F7F);
    __syncthreads();
  }

  const int cbase = n0 + wn + l15;
  if constexpr (MODE == 2) {
    float* rs = (float*)lds_all;  // [128][33] floats (dead GEMM LDS)
#pragma unroll
    for (int mf = 0; mf < 4; ++mf) {
#pragma unroll
      for (int i = 0; i < 4; ++i) {
        const int rl = wm + mf * 16 + lhi * 4 + i;
        const int row = m0 + rl;
        float rsum = 0.f;
#pragma unroll
        for (int nf = 0; nf < 4; ++nf) {
          const int col = cbase + nf * 16;
          const long oidx = (long)b * sOut + (long)row * ldo + col;
          const u8 pe = f2fp8(__expf(acc[mf][nf][i] * scale));
          ((u8*)OutV)[oidx] = pe;
          rsum += fp82f(pe);  // sum what PV will actually read
        }
        rs[rl * 33 + (wn >> 2) + l15] = rsum;
      }
    }
    __syncthreads();
    if (tid < 128) {
      float s = 0.f;
#pragma unroll
      for (int j = 0; j < 32; ++j) s += rs[tid * 33 + j];
      atomicAdd(&aux[(long)b * sRes + m0 + tid], s);
    }
  } else {
    const int rbase = m0 + wm + lhi * 4;
#pragma unroll
    for (int mf = 0; mf < 4; ++mf) {
#pragma unroll
      for (int nf = 0; nf < 4; ++nf) {
#pragma unroll
        for (int i = 0; i < 4; ++i) {
          const int row = rbase + mf * 16 + i;
          const int col = cbase + nf * 16;
          const long oidx = (long)b * sOut + (long)row * ldo + col;
          const float v = acc[mf][nf][i];
          if (MODE == 0) {
            ((u8*)OutV)[oidx] = f2fp8(v + bias[col]);
          } else if (MODE == 1) {
            ((u8*)OutV)[oidx] = f2fp8(v + bias[row]);
          } else {
            ((u16*)OutV)[oidx] = f2bf(v / aux[(long)b * sRes + row]);
          }
        }
      }
    }
  }
}

// Single-pass register-resident GroupNorm + transpose -> fp8 hT.
__global__ __launch_bounds__(256) void gn_reg(
    const float* __restrict__ x, const float* __restrict__ gamma,
    const float* __restrict__ beta, u8* __restrict__ hT8) {
  const int gid = blockIdx.x;
  const int b = gid & 7;
  const int g = gid >> 3;
  const float* px = x + ((long)b * 512 + g * 16) * 2048;
  const int tid = threadIdx.x;
  const int lane = tid & 63, wid = tid >> 6;

  u32 pk[64];
  float s = 0.f, ss = 0.f;
#pragma unroll
  for (int j = 0; j < 32; ++j) {
    const float4 u = ((const float4*)px)[tid + 256 * j];
    s += (u.x + u.y) + (u.z + u.w);
    ss += (u.x * u.x + u.y * u.y) + (u.z * u.z + u.w * u.w);
    pk[2 * j] = (u32)f2bf(u.x) | ((u32)f2bf(u.y) << 16);
    pk[2 * j + 1] = (u32)f2bf(u.z) | ((u32)f2bf(u.w) << 16);
  }
#pragma unroll
  for (int off = 32; off > 0; off >>= 1) {
    s += __shfl_xor(s, off, 64);
    ss += __shfl_xor(ss, off, 64);
  }
  __shared__ float rs4[4], rss4[4], ga[16], be[16];
  if (lane == 0) { rs4[wid] = s; rss4[wid] = ss; }
  __syncthreads();
  if (tid == 0) {
    s = rs4[0] + rs4[1] + rs4[2] + rs4[3];
    ss = rss4[0] + rss4[1] + rss4[2] + rss4[3];
    const float mean = s * (1.f / 32768.f);
    const float var = ss * (1.f / 32768.f) - mean * mean;
    rs4[0] = mean;
    rss4[0] = rsqrtf(var + 1e-6f);
  }
  __syncthreads();
  if (tid < 16) {
    const float gaa = gamma[g * 16 + tid] * rss4[0];
    ga[tid] = gaa;
    be[tid] = beta[g * 16 + tid] - rs4[0] * gaa;
  }
  __syncthreads();

  float gar[16], ber[16];
#pragma unroll
  for (int c = 0; c < 16; ++c) { gar[c] = ga[c]; ber[c] = be[c]; }

#pragma unroll
  for (int p = 0; p < 2; ++p) {
#pragma unroll
    for (int r = 0; r < 4; ++r) {
      const int n = 4 * tid + r + 1024 * p;
      u8 w[16];
#pragma unroll
      for (int c = 0; c < 16; ++c) {
        const u32 word = pk[2 * (2 * c + p) + (r >> 1)];
        const float xv = bf2f((u16)(word >> (16 * (r & 1))));
        w[c] = f2fp8(xv * gar[c] + ber[c]);
      }
      *(i32x4*)(hT8 + ((long)b * 2048 + n) * 512 + g * 16) = *(i32x4*)&w[0];
    }
  }
}

// weights: wq|wk -> fp8 wqk8[1024][512], wv -> fp8 wv8, wp -> bf16 wp16.
// z==0 blocks also: bqk concat + rowsum zero.
__global__ __launch_bounds__(256) void cvt_w(const float* __restrict__ w0,
                                             const float* __restrict__ w1,
                                             const float* __restrict__ w2,
                                             const float* __restrict__ w3,
                                             const float* __restrict__ bq,
                                             const float* __restrict__ bk,
                                             float* __restrict__ bqk,
                                             float* __restrict__ rowsum,
                                             u8* __restrict__ wqk8,
                                             u8* __restrict__ wv8,
                                             u16* __restrict__ wp16) {
  const int z = blockIdx.y;
  const int i = blockIdx.x * 256 + threadIdx.x;
  if (z == 0) {
    wqk8[i] = f2fp8(w0[i]);
    if (i < 1024) bqk[i] = (i < 512) ? bq[i] : bk[i - 512];
    if (i < 16384) rowsum[i] = 0.f;
  } else if (z == 1) {
    wqk8[262144 + i] = f2fp8(w1[i]);
  } else if (z == 2) {
    wv8[i] = f2fp8(w2[i]);
  } else {
    wp16[i] = f2bf(w3[i]);
  }
}

extern "C" void kernel_launch(void* const* d_in, const int* in_sizes, int n_in,
                              void* d_out, int out_size, void* d_ws, size_t ws_size,
                              hipStream_t stream) {
  const float* x = (const float*)d_in[0];
  const float* gs = (const float*)d_in[1];
  const float* gb = (const float*)d_in[2];
  const float* wq = (const float*)d_in[3];
  const float* bq = (const float*)d_in[4];
  const float* wk = (const float*)d_in[5];
  const float* bk = (const float*)d_in[6];
  const float* wv = (const float*)d_in[7];
  const float* bv = (const float*)d_in[8];
  const float* wp = (const float*)d_in[9];
  const float* bp = (const float*)d_in[10];

  char* ws = (char*)d_ws;
  float* bqk = (float*)(ws + 4096);        // 4 KB
  float* rowsum = (float*)(ws + 12288);    // 64 KB [B*2048]
  u8* hT8 = (u8*)(ws + 131072);            // [16384, 512] fp8, 8 MB
  u8* qkT8 = hT8 + 8388608;                // [16384, 1024] fp8, 16 MB (q|k)
  u8* vv8 = qkT8 + 16777216;               // [B, 512, 2048] fp8, 8 MB
  u8* S8 = vv8 + 8388608;                  // [B, 2048, 2048] fp8, 32 MB (holds P)
  u8* wqk8 = S8 + 33554432;                // [1024,512] fp8, 512 KB
  u8* wv8 = wqk8 + 524288;                 // [512,512] fp8, 256 KB
  u16* wp16 = (u16*)(wv8 + 262144);        // [512,512] bf16, 512 KB
  u16* attnT = wp16 + 262144;              // [16384,512] bf16, 16 MB
  float* out = (float*)d_out;

  cvt_w<<<dim3(1024, 4, 1), 256, 0, stream>>>(wq, wk, wv, wp, bq, bk, bqk, rowsum,
                                              wqk8, wv8, wp16);
  gn_reg<<<dim3(256), 256, 0, stream>>>(x, gs, gb, hT8);

  // qk: MX fp8, M=16384 (m0=by*128+b*2048), N=1024, K=512; 1024 blocks; bias[col]
  gemm_mx<0><<<dim3(1024), 256, 0, stream>>>(
      hT8, wqk8, qkT8, bqk, nullptr, 512, 512, 512, 1024, 8, 2048, 0, 0, 0, 0, 0.f);
  // v: MX fp8, M=512, N=2048, K=512; per-b 4m x 16n -> 512 blocks; bias[row]
  gemm_mx<1><<<dim3(512), 256, 0, stream>>>(
      wv8, hT8, vv8, bv, nullptr, 512, 512, 512, 2048, 16, 0, 0, 1048576,
      1048576, 0, 0.f);
  // S: MX fp8, M=N=2048, K=512; per-b 16m x 16n -> 2048 blocks; exp + rowsum
  gemm_mx<2><<<dim3(2048), 256, 0, stream>>>(
      qkT8, qkT8 + 512, S8, nullptr, rowsum, 512, 1024, 1024, 2048, 16, 0, 2097152,
      2097152, 4194304, 2048, 0.04419417382415922f);
  // PV: MX fp8, M=2048, N=512, K=2048; per-b 16m x 4n -> 512 blocks; / rowsum
  gemm_mx<5><<<dim3(512), 256, 0, stream>>>(
      S8, vv8, attnT, nullptr, rowsum, 2048, 2048, 2048, 512, 4, 0, 4194304, 1048576,
      1048576, 2048, 0.f);
  // proj+residual: bf16, M=512, N=2048, K=512; per-b 4m x 16n -> 512 blocks
  gemm13<4><<<dim3(512), 256, 0, stream>>>(
      wp16, attnT, out, bp, (float*)x, 512, 512, 512, 2048, 16, 0, 0, 1048576,
      1048576, 1048576, 0.f);
}

// Round 23
// 116.536 us; speedup vs baseline: 1.3398x; 1.0346x over previous
//
#include <hip/hip_runtime.h>
#include <hip/hip_bf16.h>
#include <hip/hip_fp8.h>

// AttnBlock: B=8, C=512, N=2048, G=32.
// R23 = R22 (120.6us) + proj moved to the MX-fp8 path (last bf16 GEMM removed):
//   - PV writes attnT as fp8 (half write traffic);
//   - wp quantized to fp8 in cvt_w;
//   - proj = gemm_mx<4>: f32 out = acc + bias[row] + residual x.
// All five GEMMs now run mfma_scale_f32_16x16x128_f8f6f4 (scale=1.0 pinned).
// Keeps: fused exp+rowsum softmax (S), /rowsum (PV), gn_reg fp8 GroupNorm,
// T2 swizzle, batch->XCD pinning, m97 128x128 structure.

typedef __attribute__((ext_vector_type(8))) short short8;
typedef __attribute__((ext_vector_type(4))) float f32x4;
typedef __attribute__((ext_vector_type(8))) int i32x8;
typedef __attribute__((ext_vector_type(4))) int i32x4;
typedef unsigned short u16;
typedef unsigned char u8;
typedef unsigned int u32;

__device__ __forceinline__ u16 f2bf(float f) {
  __hip_bfloat16 h = __float2bfloat16(f);
  return __builtin_bit_cast(u16, h);
}
__device__ __forceinline__ float bf2f(u16 u) {
  return __uint_as_float(((u32)u) << 16);
}
__device__ __forceinline__ u8 f2fp8(float f) {
  __hip_fp8_e4m3 h(f);
  return __builtin_bit_cast(u8, h);
}
__device__ __forceinline__ float fp82f(u8 u) {
  __hip_fp8_e4m3 h = __builtin_bit_cast(__hip_fp8_e4m3, u);
  return (float)h;
}

__device__ __forceinline__ void gload_lds16(const void* g, void* l) {
  __builtin_amdgcn_global_load_lds((const __attribute__((address_space(1))) void*)g,
                                   (__attribute__((address_space(3))) void*)l, 16, 0, 0);
}

// MX-scaled fp8 GEMM. K-tile = 128 fp8 elements = 128B rows; scale=1.0 pinned.
// MODE 0: fp8 out = acc + bias[col]       MODE 1: fp8 out = acc + bias[row]
// MODE 2: fp8 out = exp(acc*scale); LDS rowsum reduce -> 1 atomicAdd/row
// MODE 4: f32 out = acc + bias[row] + aux[b*sRes + row*ldo + col] (residual)
// MODE 5: fp8 out = acc / aux[b*sRes + row]
template <int MODE>
__global__ __launch_bounds__(256) void gemm_mx(
    const u8* __restrict__ A, const u8* __restrict__ Bt, void* __restrict__ OutV,
    const float* __restrict__ bias, float* __restrict__ aux,
    int K, int lda, int ldb, int ldo, int GX, int mOffB,
    long sA, long sBt, long sOut, long sRes, float scale) {
  __shared__ __align__(16) u8 lds_all[2 * 128 * 128];  // 32 KB: As | Bs
  u8* As = lds_all;
  u8* Bs = lds_all + 128 * 128;

  const int gid = blockIdx.x;
  const int b = gid & 7;  // batch == XCD (round-robin dispatch)
  const int t0 = gid >> 3;
  const int bx = t0 % GX;
  const int by = t0 / GX;
  const u8* Ab = A + (long)b * sA;
  const u8* Bb = Bt + (long)b * sBt;
  const int tid = threadIdx.x;
  const int lane = tid & 63;
  const int wid = tid >> 6;
  const int wm = (wid >> 1) * 64;
  const int wn = (wid & 1) * 64;
  const int m0 = by * 128 + b * mOffB;
  const int n0 = bx * 128;
  const int l15 = lane & 15;
  const int lhi = lane >> 4;
  const int sw = l15 & 7;
  const int slo = ((2 * lhi) ^ sw) * 16;
  const int shi = ((2 * lhi + 1) ^ sw) * 16;

  f32x4 acc[4][4];
#pragma unroll
  for (int i = 0; i < 4; ++i)
#pragma unroll
    for (int j = 0; j < 4; ++j) acc[i][j] = (f32x4){0.f, 0.f, 0.f, 0.f};

  const int T = K / 128;
  for (int t = 0; t < T; ++t) {
    const int ks = t * 128;
#pragma unroll
    for (int i = 0; i < 4; ++i) {
      const int c = tid + i * 256;
      const int row = c >> 3;
      const int gslot = (c & 7) ^ (row & 7);
      gload_lds16(Ab + (long)(m0 + row) * lda + ks + gslot * 16, (void*)(As + c * 16));
    }
#pragma unroll
    for (int i = 0; i < 4; ++i) {
      const int c = tid + i * 256;
      const int row = c >> 3;
      const int gslot = (c & 7) ^ (row & 7);
      gload_lds16(Bb + (long)(n0 + row) * ldb + ks + gslot * 16, (void*)(Bs + c * 16));
    }
    __syncthreads();

    i32x8 af[4], bf[4];
#pragma unroll
    for (int mf = 0; mf < 4; ++mf) {
      const u8* base = As + (wm + mf * 16 + l15) * 128;
      const i32x4 lo = *(const i32x4*)(base + slo);
      const i32x4 hi = *(const i32x4*)(base + shi);
      af[mf][0] = lo[0]; af[mf][1] = lo[1]; af[mf][2] = lo[2]; af[mf][3] = lo[3];
      af[mf][4] = hi[0]; af[mf][5] = hi[1]; af[mf][6] = hi[2]; af[mf][7] = hi[3];
    }
#pragma unroll
    for (int nf = 0; nf < 4; ++nf) {
      const u8* base = Bs + (wn + nf * 16 + l15) * 128;
      const i32x4 lo = *(const i32x4*)(base + slo);
      const i32x4 hi = *(const i32x4*)(base + shi);
      bf[nf][0] = lo[0]; bf[nf][1] = lo[1]; bf[nf][2] = lo[2]; bf[nf][3] = lo[3];
      bf[nf][4] = hi[0]; bf[nf][5] = hi[1]; bf[nf][6] = hi[2]; bf[nf][7] = hi[3];
    }
#pragma unroll
    for (int mf = 0; mf < 4; ++mf)
#pragma unroll
      for (int nf = 0; nf < 4; ++nf)
        acc[mf][nf] = __builtin_amdgcn_mfma_scale_f32_16x16x128_f8f6f4(
            af[mf], bf[nf], acc[mf][nf], 0, 0, 0, 0x7F7F7F7F, 0, 0x7F7F7F7F);
    __syncthreads();
  }

  const int cbase = n0 + wn + l15;
  if constexpr (MODE == 2) {
    float* rs = (float*)lds_all;  // [128][33] floats (dead GEMM LDS)
#pragma unroll
    for (int mf = 0; mf < 4; ++mf) {
#pragma unroll
      for (int i = 0; i < 4; ++i) {
        const int rl = wm + mf * 16 + lhi * 4 + i;
        const int row = m0 + rl;
        float rsum = 0.f;
#pragma unroll
        for (int nf = 0; nf < 4; ++nf) {
          const int col = cbase + nf * 16;
          const long oidx = (long)b * sOut + (long)row * ldo + col;
          const u8 pe = f2fp8(__expf(acc[mf][nf][i] * scale));
          ((u8*)OutV)[oidx] = pe;
          rsum += fp82f(pe);  // sum what PV will actually read
        }
        rs[rl * 33 + (wn >> 2) + l15] = rsum;
      }
    }
    __syncthreads();
    if (tid < 128) {
      float s = 0.f;
#pragma unroll
      for (int j = 0; j < 32; ++j) s += rs[tid * 33 + j];
      atomicAdd(&aux[(long)b * sRes + m0 + tid], s);
    }
  } else {
    const int rbase = m0 + wm + lhi * 4;
#pragma unroll
    for (int mf = 0; mf < 4; ++mf) {
#pragma unroll
      for (int nf = 0; nf < 4; ++nf) {
#pragma unroll
        for (int i = 0; i < 4; ++i) {
          const int row = rbase + mf * 16 + i;
          const int col = cbase + nf * 16;
          const long oidx = (long)b * sOut + (long)row * ldo + col;
          const float v = acc[mf][nf][i];
          if (MODE == 0) {
            ((u8*)OutV)[oidx] = f2fp8(v + bias[col]);
          } else if (MODE == 1) {
            ((u8*)OutV)[oidx] = f2fp8(v + bias[row]);
          } else if (MODE == 5) {
            ((u8*)OutV)[oidx] = f2fp8(v / aux[(long)b * sRes + row]);
          } else {  // MODE 4
            const float r = aux[(long)b * sRes + (long)row * ldo + col];
            ((float*)OutV)[oidx] = v + bias[row] + r;
          }
        }
      }
    }
  }
}

// Single-pass register-resident GroupNorm + transpose -> fp8 hT (R22-proven).
__global__ __launch_bounds__(256) void gn_reg(
    const float* __restrict__ x, const float* __restrict__ gamma,
    const float* __restrict__ beta, u8* __restrict__ hT8) {
  const int gid = blockIdx.x;
  const int b = gid & 7;
  const int g = gid >> 3;
  const float* px = x + ((long)b * 512 + g * 16) * 2048;
  const int tid = threadIdx.x;
  const int lane = tid & 63, wid = tid >> 6;

  u32 pk[64];
  float s = 0.f, ss = 0.f;
#pragma unroll
  for (int j = 0; j < 32; ++j) {
    const float4 u = ((const float4*)px)[tid + 256 * j];
    s += (u.x + u.y) + (u.z + u.w);
    ss += (u.x * u.x + u.y * u.y) + (u.z * u.z + u.w * u.w);
    pk[2 * j] = (u32)f2bf(u.x) | ((u32)f2bf(u.y) << 16);
    pk[2 * j + 1] = (u32)f2bf(u.z) | ((u32)f2bf(u.w) << 16);
  }
#pragma unroll
  for (int off = 32; off > 0; off >>= 1) {
    s += __shfl_xor(s, off, 64);
    ss += __shfl_xor(ss, off, 64);
  }
  __shared__ float rs4[4], rss4[4], ga[16], be[16];
  if (lane == 0) { rs4[wid] = s; rss4[wid] = ss; }
  __syncthreads();
  if (tid == 0) {
    s = rs4[0] + rs4[1] + rs4[2] + rs4[3];
    ss = rss4[0] + rss4[1] + rss4[2] + rss4[3];
    const float mean = s * (1.f / 32768.f);
    const float var = ss * (1.f / 32768.f) - mean * mean;
    rs4[0] = mean;
    rss4[0] = rsqrtf(var + 1e-6f);
  }
  __syncthreads();
  if (tid < 16) {
    const float gaa = gamma[g * 16 + tid] * rss4[0];
    ga[tid] = gaa;
    be[tid] = beta[g * 16 + tid] - rs4[0] * gaa;
  }
  __syncthreads();

  float gar[16], ber[16];
#pragma unroll
  for (int c = 0; c < 16; ++c) { gar[c] = ga[c]; ber[c] = be[c]; }

#pragma unroll
  for (int p = 0; p < 2; ++p) {
#pragma unroll
    for (int r = 0; r < 4; ++r) {
      const int n = 4 * tid + r + 1024 * p;
      u8 w[16];
#pragma unroll
      for (int c = 0; c < 16; ++c) {
        const u32 word = pk[2 * (2 * c + p) + (r >> 1)];
        const float xv = bf2f((u16)(word >> (16 * (r & 1))));
        w[c] = f2fp8(xv * gar[c] + ber[c]);
      }
      *(i32x4*)(hT8 + ((long)b * 2048 + n) * 512 + g * 16) = *(i32x4*)&w[0];
    }
  }
}

// weights: wq|wk -> fp8 wqk8[1024][512], wv -> fp8 wv8, wp -> fp8 wp8.
// z==0 blocks also: bqk concat + rowsum zero.
__global__ __launch_bounds__(256) void cvt_w(const float* __restrict__ w0,
                                             const float* __restrict__ w1,
                                             const float* __restrict__ w2,
                                             const float* __restrict__ w3,
                                             const float* __restrict__ bq,
                                             const float* __restrict__ bk,
                                             float* __restrict__ bqk,
                                             float* __restrict__ rowsum,
                                             u8* __restrict__ wqk8,
                                             u8* __restrict__ wv8,
                                             u8* __restrict__ wp8) {
  const int z = blockIdx.y;
  const int i = blockIdx.x * 256 + threadIdx.x;
  if (z == 0) {
    wqk8[i] = f2fp8(w0[i]);
    if (i < 1024) bqk[i] = (i < 512) ? bq[i] : bk[i - 512];
    if (i < 16384) rowsum[i] = 0.f;
  } else if (z == 1) {
    wqk8[262144 + i] = f2fp8(w1[i]);
  } else if (z == 2) {
    wv8[i] = f2fp8(w2[i]);
  } else {
    wp8[i] = f2fp8(w3[i]);
  }
}

extern "C" void kernel_launch(void* const* d_in, const int* in_sizes, int n_in,
                              void* d_out, int out_size, void* d_ws, size_t ws_size,
                              hipStream_t stream) {
  const float* x = (const float*)d_in[0];
  const float* gs = (const float*)d_in[1];
  const float* gb = (const float*)d_in[2];
  const float* wq = (const float*)d_in[3];
  const float* bq = (const float*)d_in[4];
  const float* wk = (const float*)d_in[5];
  const float* bk = (const float*)d_in[6];
  const float* wv = (const float*)d_in[7];
  const float* bv = (const float*)d_in[8];
  const float* wp = (const float*)d_in[9];
  const float* bp = (const float*)d_in[10];

  char* ws = (char*)d_ws;
  float* bqk = (float*)(ws + 4096);        // 4 KB
  float* rowsum = (float*)(ws + 12288);    // 64 KB [B*2048]
  u8* hT8 = (u8*)(ws + 131072);            // [16384, 512] fp8, 8 MB
  u8* qkT8 = hT8 + 8388608;                // [16384, 1024] fp8, 16 MB (q|k)
  u8* vv8 = qkT8 + 16777216;               // [B, 512, 2048] fp8, 8 MB
  u8* S8 = vv8 + 8388608;                  // [B, 2048, 2048] fp8, 32 MB (holds P)
  u8* wqk8 = S8 + 33554432;                // [1024,512] fp8, 512 KB
  u8* wv8 = wqk8 + 524288;                 // [512,512] fp8, 256 KB
  u8* wp8 = wv8 + 262144;                  // [512,512] fp8, 256 KB
  u8* attnT8 = wp8 + 262144;               // [16384,512] fp8, 8 MB
  float* out = (float*)d_out;

  cvt_w<<<dim3(1024, 4, 1), 256, 0, stream>>>(wq, wk, wv, wp, bq, bk, bqk, rowsum,
                                              wqk8, wv8, wp8);
  gn_reg<<<dim3(256), 256, 0, stream>>>(x, gs, gb, hT8);

  // qk: M=16384 (m0=by*128+b*2048), N=1024, K=512; 1024 blocks; bias[col] -> fp8
  gemm_mx<0><<<dim3(1024), 256, 0, stream>>>(
      hT8, wqk8, qkT8, bqk, nullptr, 512, 512, 512, 1024, 8, 2048, 0, 0, 0, 0, 0.f);
  // v: M=512, N=2048, K=512; per-b 4m x 16n -> 512 blocks; bias[row] -> fp8
  gemm_mx<1><<<dim3(512), 256, 0, stream>>>(
      wv8, hT8, vv8, bv, nullptr, 512, 512, 512, 2048, 16, 0, 0, 1048576,
      1048576, 0, 0.f);
  // S: M=N=2048, K=512; per-b 16m x 16n -> 2048 blocks; exp + rowsum -> fp8
  gemm_mx<2><<<dim3(2048), 256, 0, stream>>>(
      qkT8, qkT8 + 512, S8, nullptr, rowsum, 512, 1024, 1024, 2048, 16, 0, 2097152,
      2097152, 4194304, 2048, 0.04419417382415922f);
  // PV: M=2048, N=512, K=2048; per-b 16m x 4n -> 512 blocks; / rowsum -> fp8
  gemm_mx<5><<<dim3(512), 256, 0, stream>>>(
      S8, vv8, attnT8, nullptr, rowsum, 2048, 2048, 2048, 512, 4, 0, 4194304, 1048576,
      1048576, 2048, 0.f);
  // proj+residual: M=512, N=2048, K=512; per-b 4m x 16n -> 512 blocks; f32 out
  gemm_mx<4><<<dim3(512), 256, 0, stream>>>(
      wp8, attnT8, out, bp, (float*)x, 512, 512, 512, 2048, 16, 0, 0, 1048576,
      1048576, 1048576, 0.f);
}